// Round 6
// baseline (771.313 us; speedup 1.0000x reference)
//
#include <hip/hip_runtime.h>
#include <math.h>

// LSTM fused: H=32, D=1, B=4096, T=1024 — MFMA-recurrence structure.
//
// R1-R5 lesson: all VALU-dot variants plateau at ~285 cyc/batch-step because
// v_dot2_f32_f16 is half-rate (2 MAC / 4 cyc = fp32 fma MAC rate) and the
// 4096 independent chains cap waves x ILP. This round moves the h@W_hh^T to
// the MFMA pipe (v_mfma_f32_16x16x32_f16: 8192 MAC/inst) and spreads
// activations to 1 (batch,unit) state per thread:
//
//   block = 256 threads, 8 batches; 512 blocks = 2 blocks/CU.
//   step: [act: thread reads its 4 gate preacts from LDS, 5 sigmoid/tanh,
//          c,h update, h->LDS fp16] barrier
//         [mfma: each wave does 2 of 8 M-tiles of W_hh(128x32) @ h(32x16),
//          A-frags in VGPRs, B-frag = one ds_read_b128, C -> gates LDS]
//         barrier
//   x staged in 256-step fp16 chunks, refilled inside the mfma window.
//
// Fragment layouts (verified m89/m91/m120): A[m=lane&15][k=quad*8+j],
// B[k=quad*8+j][n=lane&15], C: col(n)=lane&15, row(m)=quad*4+reg.

#define HH 32
#define TT 1024
#define BPB 8           // batches per block
#define NT  256
#define CHUNK 256       // x-staging chunk (timesteps)

typedef _Float16 half8 __attribute__((ext_vector_type(8)));
typedef float    f32x4 __attribute__((ext_vector_type(4)));

__device__ __forceinline__ float fast_sigmoid(float x) {
    float e = __builtin_amdgcn_exp2f(x * -1.4426950408889634f);
    return __builtin_amdgcn_rcpf(1.0f + e);
}

__device__ __forceinline__ float fast_tanh(float x) {
    float e = __builtin_amdgcn_exp2f(x * -2.8853900817779268f);
    return fmaf(2.0f, __builtin_amdgcn_rcpf(1.0f + e), -1.0f);
}

__global__ __launch_bounds__(NT, 2)
void lstm_mfma(const float* __restrict__ x,
               const float* __restrict__ W_ih,
               const float* __restrict__ W_hh,
               const float* __restrict__ b_ih,
               const float* __restrict__ b_hh,
               const float* __restrict__ fc_W,
               const float* __restrict__ fc_b,
               float* __restrict__ out)
{
    // gates sized 16 batches: MFMA writes all 16 N-cols; cols 8..15 unused.
    __shared__ __align__(16) float    gates[16 * 128];   // [b][gate-row] f32, 8 KB
    __shared__ __align__(16) _Float16 hsh[16 * HH];      // [b][unit] fp16, 1 KB
    __shared__ __align__(16) _Float16 xc[BPB * CHUNK];   // x chunk fp16, 4 KB

    const int tid  = threadIdx.x;
    const int wave = tid >> 6;
    const int lane = tid & 63;
    const int b    = tid >> 5;          // act mapping: batch 0..7
    const int u    = tid & 31;          // unit 0..31
    const int b0   = blockIdx.x * BPB;

    // ---- per-thread act constants (gate order i,f,g,o) ----
    float wx[4], bb[4];
    #pragma unroll
    for (int g = 0; g < 4; ++g) {
        wx[g] = W_ih[g * HH + u];                       // D == 1
        bb[g] = b_ih[g * HH + u] + b_hh[g * HH + u];
    }

    // ---- A-fragments: wave w owns M-tiles {2w, 2w+1} of W_hh (128x32) ----
    // A[m=lane&15][k=quad*8+j], tile tau covers rows 16*tau .. 16*tau+15.
    const int m    = lane & 15;
    const int quad = lane >> 4;
    half8 afrag[2];
    #pragma unroll
    for (int s = 0; s < 2; ++s) {
        const int tau = 2 * wave + s;
        const float* row = W_hh + (size_t)(16 * tau + m) * HH + quad * 8;
        #pragma unroll
        for (int j = 0; j < 8; ++j)
            afrag[s][j] = (_Float16)row[j];
    }

    // ---- zero LDS state ----
    for (int i = tid; i < 16 * 128; i += NT) gates[i] = 0.0f;
    for (int i = tid; i < 16 * HH;  i += NT) hsh[i]   = (_Float16)0.0f;

    // ---- load x chunk 0 (fp32 coalesced -> fp16 LDS) ----
    #pragma unroll
    for (int k = tid; k < BPB * CHUNK; k += NT)
        xc[k] = (_Float16)x[(size_t)(b0 + (k >> 8)) * TT + (k & 255)];

    float c = 0.0f;
    __syncthreads();

    const _Float16* hrow = &hsh[(lane & 15) * HH + quad * 8];   // B-frag source
    float* gcol = &gates[(lane & 15) * 128 + quad * 4];          // C-frag dest

    #pragma unroll 1
    for (int t = 0; t < TT; ++t) {
        // ================= act phase: 1 state per thread =================
        const float xv = (float)xc[b * CHUNK + (t & 255)];
        const float r0 = gates[b * 128 + u];
        const float r1 = gates[b * 128 + 32 + u];
        const float r2 = gates[b * 128 + 64 + u];
        const float r3 = gates[b * 128 + 96 + u];
        const float p0 = fmaf(xv, wx[0], r0 + bb[0]);
        const float p1 = fmaf(xv, wx[1], r1 + bb[1]);
        const float p2 = fmaf(xv, wx[2], r2 + bb[2]);
        const float p3 = fmaf(xv, wx[3], r3 + bb[3]);

        const float gi = fast_sigmoid(p0);
        const float gf = fast_sigmoid(p1);
        const float gg = fast_tanh(p2);
        const float go = fast_sigmoid(p3);
        c = fmaf(gf, c, gi * gg);
        const float h = go * fast_tanh(c);

        hsh[b * HH + u] = (_Float16)h;
        __syncthreads();   // h visible; gates(t) reads done

        // ============== mfma phase: gates(t+1) = W_hh @ h(t) =============
        if (t + 1 < TT) {
            // B[k=quad*8+j][n=lane&15] = h[batch n][unit k] — one b128 read.
            const half8 bf = *(const half8*)hrow;
            const f32x4 zero = {0.0f, 0.0f, 0.0f, 0.0f};
            #pragma unroll
            for (int s = 0; s < 2; ++s) {
                const int tau = 2 * wave + s;
                f32x4 acc = __builtin_amdgcn_mfma_f32_16x16x32_f16(
                                afrag[s], bf, zero, 0, 0, 0);
                // C: col=lane&15 (batch), rows 16*tau + quad*4 + r.
                *(f32x4*)(gcol + 16 * tau) = acc;
            }
            // x chunk refill, overlapped into this window.
            if ((t & 255) == 255) {
                const int cn = (t + 1) >> 8;
                #pragma unroll
                for (int k = tid; k < BPB * CHUNK; k += NT)
                    xc[k] = (_Float16)x[(size_t)(b0 + (k >> 8)) * TT
                                        + cn * CHUNK + (k & 255)];
            }
        }
        __syncthreads();   // gates(t+1) visible
    }

    // ---- epilogue: out[b] = fc_W . h + fc_b ----
    if (tid < BPB) {
        float acc = fc_b[0];
        #pragma unroll
        for (int u2 = 0; u2 < HH; ++u2)
            acc += (float)hsh[tid * HH + u2] * fc_W[u2];
        out[b0 + tid] = acc;
    }
}

extern "C" void kernel_launch(void* const* d_in, const int* in_sizes, int n_in,
                              void* d_out, int out_size, void* d_ws, size_t ws_size,
                              hipStream_t stream) {
    const float* x    = (const float*)d_in[0];
    const float* W_ih = (const float*)d_in[1];
    const float* W_hh = (const float*)d_in[2];
    const float* b_ih = (const float*)d_in[3];
    const float* b_hh = (const float*)d_in[4];
    const float* fc_W = (const float*)d_in[5];
    const float* fc_b = (const float*)d_in[6];
    float* out = (float*)d_out;

    const int B = in_sizes[0] / TT;   // 4096 (D == 1)
    dim3 grid(B / BPB), block(NT);
    lstm_mfma<<<grid, block, 0, stream>>>(x, W_ih, W_hh, b_ih, b_hh,
                                          fc_W, fc_b, out);
}

// Round 7
// 753.455 us; speedup vs baseline: 1.0237x; 1.0237x over previous
//
#include <hip/hip_runtime.h>
#include <math.h>

// LSTM fused: H=32, D=1, B=4096, T=1024 — wave-autonomous MFMA recurrence.
//
// R6 lesson: the block-wide 2-barrier MFMA structure died on (a) 16-way LDS
// bank conflicts in the C-writeback ((lane&15)*128 = 0 mod 32) = 53% of the
// wall, and (b) barrier-serialized latency (VALU 22%, MFMA 4%).
//
// This round: one wave owns 2 batches end-to-end; no __syncthreads at all.
//   A-frags: W_hh (128x32) as 8 16x16x32 tiles in VGPRs (replicated/wave).
//   Per step (all intra-wave, ordered by lgkmcnt):
//     ds_read_b128 h -> 8x mfma_f32_16x16x32_f16 (cols 0..1 real) ->
//     scatter C to gbuf (stride 132: 2-way max, free) ->
//     1 state/lane act (4 gate reads, 5 transcendental evals, c/h update) ->
//     ds_write_b16 h.
//   Grid 2048 waves = 2/SIMD: co-resident waves hide each other's serial
//   latency (MFMA tail ~155cyc, trans chain, LDS waits) per m114.
// Fragment layouts (m89/m91/m120-verified): A[m=lane&15][k=quad*8+j],
// B[k=quad*8+j][n=lane&15], C: col=lane&15, row=quad*4+reg.

#define HH 32
#define TT 1024
#define BPW 2               // batches per wave
#define WPB 4               // waves per block
#define BPB (BPW * WPB)     // 8 batches per block
#define NT 256
#define GSTRIDE 132         // gbuf batch stride in f32 (128 + 4 pad)

typedef _Float16 half8 __attribute__((ext_vector_type(8)));
typedef float    f32x4 __attribute__((ext_vector_type(4)));

__device__ __forceinline__ float fast_sigmoid(float x) {
    float e = __builtin_amdgcn_exp2f(x * -1.4426950408889634f);
    return __builtin_amdgcn_rcpf(1.0f + e);
}

__device__ __forceinline__ float fast_tanh(float x) {
    float e = __builtin_amdgcn_exp2f(x * -2.8853900817779268f);
    return fmaf(2.0f, __builtin_amdgcn_rcpf(1.0f + e), -1.0f);
}

__global__ __attribute__((amdgpu_flat_work_group_size(NT, NT),
                          amdgpu_waves_per_eu(2, 2)))
void lstm_wmfma(const float* __restrict__ x,
                const float* __restrict__ W_ih,
                const float* __restrict__ W_hh,
                const float* __restrict__ b_ih,
                const float* __restrict__ b_hh,
                const float* __restrict__ fc_W,
                const float* __restrict__ fc_b,
                float* __restrict__ out)
{
    // Per-wave-private LDS regions (no cross-wave sharing, no barriers).
    __shared__ _Float16 xw[WPB][BPW * TT];        // 16 KB: x as fp16
    __shared__ _Float16 hsh[WPB][BPW * HH];       // 512 B: h(t) fp16
    __shared__ float    gbuf[WPB][BPW * GSTRIDE]; // 4.2 KB: gate preacts

    const int tid  = threadIdx.x;
    const int wv   = tid >> 6;
    const int lane = tid & 63;
    const int n    = lane & 15;     // MFMA col (batch; real for n < BPW)
    const int q    = lane >> 4;     // quad
    const int b    = lane >> 5;     // act mapping: batch 0..1
    const int u    = lane & 31;     // act mapping: hidden unit
    const int gb0  = blockIdx.x * BPB + wv * BPW;   // wave's first batch

    // ---- stage this wave's x rows into LDS as fp16 (wave-private, coalesced) ----
    {
        const float4* xg = (const float4*)(x + (size_t)gb0 * TT);
        #pragma unroll
        for (int it = 0; it < (BPW * TT / 4) / 64; ++it) {
            const float4 v = xg[it * 64 + lane];
            half8 dummy;  // pack 4 halves
            _Float16 h0 = (_Float16)v.x, h1 = (_Float16)v.y;
            _Float16 h2 = (_Float16)v.z, h3 = (_Float16)v.w;
            _Float16* dst = &xw[wv][(it * 64 + lane) * 4];
            dst[0] = h0; dst[1] = h1; dst[2] = h2; dst[3] = h3;
            (void)dummy;
        }
    }

    // ---- A-fragments: 8 M-tiles of W_hh (rows = gate-rows 0..127) ----
    // A[m=lane&15][k=quad*8+j] for tile tau covering rows 16*tau..16*tau+15.
    half8 afrag[8];
    #pragma unroll
    for (int tau = 0; tau < 8; ++tau) {
        const float* row = W_hh + (size_t)(16 * tau + n) * HH + q * 8;
        #pragma unroll
        for (int j = 0; j < 8; ++j)
            afrag[tau][j] = (_Float16)row[j];
    }

    // ---- act-side constants for this lane's (b,u) state ----
    float wx[4], bb[4];
    #pragma unroll
    for (int g = 0; g < 4; ++g) {
        wx[g] = W_ih[g * HH + u];                    // D == 1
        bb[g] = b_ih[g * HH + u] + b_hh[g * HH + u];
    }

    // ---- init h(0) = 0 (each lane covers its own (b,u) slot) ----
    hsh[wv][b * HH + u] = (_Float16)0.0f;
    float c = 0.0f, h = 0.0f;

    // B-frag source: lane reads h[col n&1][units 8q..8q+7] — 8 distinct
    // addresses, same-address broadcast, distinct banks -> conflict-free.
    const half8* bsrc = (const half8*)&hsh[wv][(n & 1) * HH + q * 8];
    const bool   cwr  = (n < BPW);                  // C-scatter writer lanes
    float*       gw   = &gbuf[wv][n * GSTRIDE + q * 4];
    const float* gr   = &gbuf[wv][b * GSTRIDE + u];
    const _Float16* xr = &xw[wv][b * TT];

    #pragma unroll 1
    for (int t = 0; t < TT; ++t) {
        // ---- gates(t) = W_hh @ h(t-1)  (h read after prev-step write; lgkm) ----
        const half8 bf = *bsrc;
        const f32x4 zero = {0.0f, 0.0f, 0.0f, 0.0f};
        f32x4 acc[8];
        #pragma unroll
        for (int tau = 0; tau < 8; ++tau)
            acc[tau] = __builtin_amdgcn_mfma_f32_16x16x32_f16(
                           afrag[tau], bf, zero, 0, 0, 0);

        // ---- scatter C: gbuf[n][16*tau + 4q + r] (stride 132 -> <=2-way) ----
        if (cwr) {
            #pragma unroll
            for (int tau = 0; tau < 8; ++tau)
                *(f32x4*)(gw + 16 * tau) = acc[tau];
        }

        // ---- act: 1 (batch,unit) state per lane ----
        const float xv = (float)xr[t];
        const float g0 = gr[0];
        const float g1 = gr[32];
        const float g2 = gr[64];
        const float g3 = gr[96];
        const float p0 = fmaf(xv, wx[0], g0 + bb[0]);
        const float p1 = fmaf(xv, wx[1], g1 + bb[1]);
        const float p2 = fmaf(xv, wx[2], g2 + bb[2]);
        const float p3 = fmaf(xv, wx[3], g3 + bb[3]);

        const float gi = fast_sigmoid(p0);
        const float gf = fast_sigmoid(p1);
        const float gg = fast_tanh(p2);
        const float go = fast_sigmoid(p3);
        c = fmaf(gf, c, gi * gg);
        h = go * fast_tanh(c);

        hsh[wv][b * HH + u] = (_Float16)h;   // h(t) for next step's B-frag
    }

    // ---- epilogue: out[gb] = fc_W . h + fc_b, reduce over the 32-lane group ----
    float p = h * fc_W[u];
    #pragma unroll
    for (int m = 16; m >= 1; m >>= 1)
        p += __shfl_xor(p, m, 32);
    if (u == 0)
        out[gb0 + b] = p + fc_b[0];
}

extern "C" void kernel_launch(void* const* d_in, const int* in_sizes, int n_in,
                              void* d_out, int out_size, void* d_ws, size_t ws_size,
                              hipStream_t stream) {
    const float* x    = (const float*)d_in[0];
    const float* W_ih = (const float*)d_in[1];
    const float* W_hh = (const float*)d_in[2];
    const float* b_ih = (const float*)d_in[3];
    const float* b_hh = (const float*)d_in[4];
    const float* fc_W = (const float*)d_in[5];
    const float* fc_b = (const float*)d_in[6];
    float* out = (float*)d_out;

    const int B = in_sizes[0] / TT;   // 4096 (D == 1)
    dim3 grid(B / BPB), block(NT);
    lstm_wmfma<<<grid, block, 0, stream>>>(x, W_ih, W_hh, b_ih, b_hh,
                                           fc_W, fc_b, out);
}

// Round 8
// 437.380 us; speedup vs baseline: 1.7635x; 1.7227x over previous
//
#include <hip/hip_runtime.h>
#include <math.h>

// LSTM fused: H=32, D=1, B=4096, T=1024 — MFMA with in-register C extraction.
//
// R7 lesson: LDS pipe (1/CU, shared by 8 waves) was the wall — the C
// scatter/gather to redistribute MFMA output cost ~150-200 DS-cyc/wave-step.
// This round eliminates ALL per-step LDS traffic except 3 ops:
//   - B columns replicate the wave's 2 batches 8x (col n -> batch n&1), so
//     every lane receives a full gate set for its batch.
//   - A-tiles reordered: afrag[tau] = W_hh rows [32*(tau&3)+16*(tau>>2), +16).
//     Then lane (q, n) with s=n>>1, r=s&3, kp=s>>2 holds ALL 4 gates of state
//     u = 4q + r + 16*kp at constant reg slots: acc[g or g+4][r], selected
//     with 7 cndmask per gate (lane-uniform bools).
//   - act: exactly 1 (batch,unit) state per lane; h written back as 1
//     ds_write_b16; next B-frag = 1 broadcast ds_read_b128; x = 1 ds_read_u16.
// 512 blocks x 4 waves = 2 waves/SIMD; waves are autonomous (no barriers).
// Layout provenance: A[m=lane&15][k=quad*8+j], B[k=quad*8+j][n=lane&15],
// C col=lane&15 row=quad*4+reg — all validated by R7 (passed, absmax 9.8e-4).

#define HH 32
#define TT 1024
#define BPW 2               // batches per wave
#define WPB 4               // waves per block
#define BPB (BPW * WPB)
#define NT 256

typedef _Float16 half8 __attribute__((ext_vector_type(8)));
typedef float    f32x4 __attribute__((ext_vector_type(4)));

__device__ __forceinline__ float fast_sigmoid(float x) {
    float e = __builtin_amdgcn_exp2f(x * -1.4426950408889634f);
    return __builtin_amdgcn_rcpf(1.0f + e);
}

__device__ __forceinline__ float fast_tanh(float x) {
    float e = __builtin_amdgcn_exp2f(x * -2.8853900817779268f);
    return fmaf(2.0f, __builtin_amdgcn_rcpf(1.0f + e), -1.0f);
}

__global__ __attribute__((amdgpu_flat_work_group_size(NT, NT),
                          amdgpu_waves_per_eu(2, 2)))
void lstm_xmfma(const float* __restrict__ x,
                const float* __restrict__ W_ih,
                const float* __restrict__ W_hh,
                const float* __restrict__ b_ih,
                const float* __restrict__ b_hh,
                const float* __restrict__ fc_W,
                const float* __restrict__ fc_b,
                float* __restrict__ out)
{
    __shared__ _Float16 xw[WPB][BPW * TT];   // 16 KB: x fp16, wave-private
    __shared__ _Float16 hsh[WPB][BPW * HH];  // 512 B: h(t) fp16, wave-private

    const int tid  = threadIdx.x;
    const int wv   = tid >> 6;
    const int lane = tid & 63;
    const int q    = lane >> 4;          // quad
    const int n    = lane & 15;          // MFMA col
    const int b    = n & 1;              // this lane's batch (0/1)
    const int s    = n >> 1;             // replication slot 0..7
    const int r    = s & 3;              // C reg-component of this lane's state
    const int kp   = s >> 2;             // half-select (u < 16 vs >= 16)
    const int u    = 4 * q + r + 16 * kp;   // this lane's hidden unit
    const int gb0  = blockIdx.x * BPB + wv * BPW;

    // ---- stage this wave's 2 x-rows into LDS as fp16 (wave-private) ----
    {
        const float4* xg = (const float4*)(x + (size_t)gb0 * TT);
        #pragma unroll
        for (int it = 0; it < (BPW * TT / 4) / 64; ++it) {
            const float4 v = xg[it * 64 + lane];
            _Float16* dst = &xw[wv][(it * 64 + lane) * 4];
            dst[0] = (_Float16)v.x; dst[1] = (_Float16)v.y;
            dst[2] = (_Float16)v.z; dst[3] = (_Float16)v.w;
        }
    }

    // ---- A-fragments, tile-reordered: afrag[tau] = W_hh rows
    //      [32*(tau&3) + 16*(tau>>2), +16);  A[m=n][k=8q+j] ----
    half8 af[8];
    #pragma unroll
    for (int tau = 0; tau < 8; ++tau) {
        const int rbase = 32 * (tau & 3) + 16 * (tau >> 2);
        const float* arow = W_hh + (size_t)(rbase + n) * HH + 8 * q;
        #pragma unroll
        for (int j = 0; j < 8; ++j)
            af[tau][j] = (_Float16)arow[j];
    }

    // ---- per-lane act constants for state (b, u) ----
    float wx[4], bb[4];
    #pragma unroll
    for (int g = 0; g < 4; ++g) {
        wx[g] = W_ih[g * HH + u];                    // D == 1
        bb[g] = b_ih[g * HH + u] + b_hh[g * HH + u];
    }

    // ---- init h(0)=0: 64 lanes <-> 2 batches x 32 units, exact cover ----
    hsh[wv][b * HH + u] = (_Float16)0.0f;
    float c = 0.0f, h = 0.0f;

    const half8*    bsrc = (const half8*)&hsh[wv][b * HH + 8 * q];  // B-frag
    const _Float16* xr   = &xw[wv][b * TT];

    const bool rb0 = (r & 1) != 0;
    const bool rb1 = (r & 2) != 0;
    const bool kb  = (kp != 0);

    #pragma unroll 2
    for (int t = 0; t < TT; ++t) {
        // B[k=8q+j][col n] = h[8q+j][n&1] — broadcast, conflict-free.
        const half8 bf = *bsrc;
        const f32x4 zero = {0.0f, 0.0f, 0.0f, 0.0f};
        f32x4 acc[8];
        #pragma unroll
        for (int tau = 0; tau < 8; ++tau)
            acc[tau] = __builtin_amdgcn_mfma_f32_16x16x32_f16(
                           af[tau], bf, zero, 0, 0, 0);

        // ---- extract this lane's 4 gates from constant reg slots ----
        // acc[g + 4*kp][r] = gate g of unit u, batch b.
        float val[4];
        #pragma unroll
        for (int g = 0; g < 4; ++g) {
            const f32x4 lo = acc[g];
            const f32x4 hi = acc[g + 4];
            const float l01 = rb0 ? lo[1] : lo[0];
            const float l23 = rb0 ? lo[3] : lo[2];
            const float lv  = rb1 ? l23 : l01;
            const float h01 = rb0 ? hi[1] : hi[0];
            const float h23 = rb0 ? hi[3] : hi[2];
            const float hv  = rb1 ? h23 : h01;
            val[g] = kb ? hv : lv;
        }

        // ---- act: 1 state per lane ----
        const float xv = (float)xr[t];
        const float p0 = fmaf(xv, wx[0], val[0] + bb[0]);
        const float p1 = fmaf(xv, wx[1], val[1] + bb[1]);
        const float p2 = fmaf(xv, wx[2], val[2] + bb[2]);
        const float p3 = fmaf(xv, wx[3], val[3] + bb[3]);

        const float gi = fast_sigmoid(p0);
        const float gf = fast_sigmoid(p1);
        const float gg = fast_tanh(p2);
        const float go = fast_sigmoid(p3);
        c = fmaf(gf, c, gi * gg);
        h = go * fast_tanh(c);

        hsh[wv][b * HH + u] = (_Float16)h;   // next step's B-frag (intra-wave)
    }

    // ---- epilogue: reduce h*fc_W over each parity class (batch) ----
    float p = h * fc_W[u];
    #pragma unroll
    for (int m = 2; m <= 32; m <<= 1)
        p += __shfl_xor(p, m, 64);           // sums lanes with same bit0 (=b)
    if (lane < 2)
        out[gb0 + lane] = p + fc_b[0];       // lane 0 -> b=0, lane 1 -> b=1
}

extern "C" void kernel_launch(void* const* d_in, const int* in_sizes, int n_in,
                              void* d_out, int out_size, void* d_ws, size_t ws_size,
                              hipStream_t stream) {
    const float* x    = (const float*)d_in[0];
    const float* W_ih = (const float*)d_in[1];
    const float* W_hh = (const float*)d_in[2];
    const float* b_ih = (const float*)d_in[3];
    const float* b_hh = (const float*)d_in[4];
    const float* fc_W = (const float*)d_in[5];
    const float* fc_b = (const float*)d_in[6];
    float* out = (float*)d_out;

    const int B = in_sizes[0] / TT;   // 4096 (D == 1)
    dim3 grid(B / BPB), block(NT);
    lstm_xmfma<<<grid, block, 0, stream>>>(x, W_ih, W_hh, b_ih, b_hh,
                                           fc_W, fc_b, out);
}

// Round 9
// 421.157 us; speedup vs baseline: 1.8314x; 1.0385x over previous
//
#include <hip/hip_runtime.h>
#include <math.h>

// LSTM fused: H=32, D=1, B=4096, T=1024 — 4-batch-replicated MFMA, 2 states/lane.
//
// R8 lesson: 2 waves/SIMD of identical phase-locked code do NOT hide each
// other's serial chain (wall 1008 cyc/step vs ~400 issue). This round packs
// more independent work into ONE instruction stream:
//   - B cols replicate 4 batches (col n -> batch n&3): 8 MFMAs serve 4
//     batches (half the MFMA work per batch of R8).
//   - Natural tile order afrag[tau] = W_hh rows [16tau,16tau+16). Lane (q,n),
//     r = n>>2: gate g of unit u=4q+r is acc[2g][r]; of u+16 is acc[2g+1][r].
//     Extraction = 3 cndmask per value, 24 insts for both states.
//   - Each lane acts TWO states (batch n&3; units u, u+16): 8 independent
//     transcendental chains -> trans issue-limited, latency hidden in-wave.
//   - 256 blocks x 4 waves = 1024 waves = 1 wave/SIMD; zero barriers;
//     all latency hiding is static in-wave ILP.
// Layouts (R7/R8-validated): A[m=lane&15][k=8q+j], B[k=8q+j][n=lane&15],
// C col=lane&15, row=4*quad+reg.

#define HH 32
#define TT 1024
#define BPW 4               // batches per wave
#define WPB 4               // waves per block
#define BPB (BPW * WPB)     // 16
#define NT 256

typedef _Float16 half8 __attribute__((ext_vector_type(8)));
typedef float    f32x4 __attribute__((ext_vector_type(4)));

__device__ __forceinline__ float fast_sigmoid(float x) {
    float e = __builtin_amdgcn_exp2f(x * -1.4426950408889634f);
    return __builtin_amdgcn_rcpf(1.0f + e);
}

__device__ __forceinline__ float fast_tanh(float x) {
    float e = __builtin_amdgcn_exp2f(x * -2.8853900817779268f);
    return fmaf(2.0f, __builtin_amdgcn_rcpf(1.0f + e), -1.0f);
}

__global__ __attribute__((amdgpu_flat_work_group_size(NT, NT),
                          amdgpu_waves_per_eu(1, 2)))
void lstm_q4(const float* __restrict__ x,
             const float* __restrict__ W_ih,
             const float* __restrict__ W_hh,
             const float* __restrict__ b_ih,
             const float* __restrict__ b_hh,
             const float* __restrict__ fc_W,
             const float* __restrict__ fc_b,
             float* __restrict__ out)
{
    __shared__ _Float16 xw[WPB][BPW * TT];   // 32 KB: x fp16, wave-private
    __shared__ _Float16 hsh[WPB][BPW * HH];  // 1 KB: h(t) fp16, wave-private

    const int tid  = threadIdx.x;
    const int wv   = tid >> 6;
    const int lane = tid & 63;
    const int q    = lane >> 4;          // quad (C row group)
    const int n    = lane & 15;          // MFMA col
    const int b    = n & 3;              // this lane's batch (0..3)
    const int r    = n >> 2;             // C reg component of this lane's states
    const int u1   = 4 * q + r;          // state 1 unit (acc[2g][r])
    const int u2   = u1 + 16;            // state 2 unit (acc[2g+1][r])
    const int gb0  = blockIdx.x * BPB + wv * BPW;

    // ---- stage this wave's 4 x-rows into LDS as fp16 (wave-private) ----
    {
        const float4* xg = (const float4*)(x + (size_t)gb0 * TT);
        #pragma unroll
        for (int it = 0; it < (BPW * TT / 4) / 64; ++it) {
            const float4 v = xg[it * 64 + lane];
            _Float16* dst = &xw[wv][(it * 64 + lane) * 4];
            dst[0] = (_Float16)v.x; dst[1] = (_Float16)v.y;
            dst[2] = (_Float16)v.z; dst[3] = (_Float16)v.w;
        }
    }

    // ---- A-fragments, natural tile order: afrag[tau] = rows [16tau,+16) ----
    half8 af[8];
    #pragma unroll
    for (int tau = 0; tau < 8; ++tau) {
        const float* arow = W_hh + (size_t)(16 * tau + n) * HH + 8 * q;
        #pragma unroll
        for (int j = 0; j < 8; ++j)
            af[tau][j] = (_Float16)arow[j];
    }

    // ---- per-lane act constants for states (b,u1) and (b,u2) ----
    float wx1[4], bb1[4], wx2[4], bb2[4];
    #pragma unroll
    for (int g = 0; g < 4; ++g) {
        wx1[g] = W_ih[g * HH + u1];
        bb1[g] = b_ih[g * HH + u1] + b_hh[g * HH + u1];
        wx2[g] = W_ih[g * HH + u2];
        bb2[g] = b_ih[g * HH + u2] + b_hh[g * HH + u2];
    }

    // ---- init h(0)=0: 64 lanes x 2 slots = all 4x32 states, exact cover ----
    hsh[wv][b * HH + u1] = (_Float16)0.0f;
    hsh[wv][b * HH + u2] = (_Float16)0.0f;
    float c1 = 0.0f, h1 = 0.0f, c2 = 0.0f, h2 = 0.0f;

    // B-frag: B[k=8q+j][col n] = h[batch n&3][unit 8q+j]; <=2-way aliasing.
    const half8*    bsrc = (const half8*)&hsh[wv][b * HH + 8 * q];
    const _Float16* xr   = &xw[wv][b * TT];

    const bool rb0 = (r & 1) != 0;
    const bool rb1 = (r & 2) != 0;

    #pragma unroll 2
    for (int t = 0; t < TT; ++t) {
        const half8 bf = *bsrc;             // broadcast ds_read_b128
        const f32x4 zero = {0.0f, 0.0f, 0.0f, 0.0f};
        f32x4 acc[8];
        #pragma unroll
        for (int tau = 0; tau < 8; ++tau)
            acc[tau] = __builtin_amdgcn_mfma_f32_16x16x32_f16(
                           af[tau], bf, zero, 0, 0, 0);

        // ---- extract 2 states x 4 gates from constant reg slots ----
        float v1[4], v2[4];
        #pragma unroll
        for (int g = 0; g < 4; ++g) {
            const f32x4 lo = acc[2 * g];        // unit u1 rows
            const f32x4 hi = acc[2 * g + 1];    // unit u2 rows
            const float l01 = rb0 ? lo[1] : lo[0];
            const float l23 = rb0 ? lo[3] : lo[2];
            v1[g] = rb1 ? l23 : l01;
            const float h01 = rb0 ? hi[1] : hi[0];
            const float h23 = rb0 ? hi[3] : hi[2];
            v2[g] = rb1 ? h23 : h01;
        }

        // ---- act: two independent states per lane ----
        const float xv = (float)xr[t];
        const float p10 = fmaf(xv, wx1[0], v1[0] + bb1[0]);
        const float p11 = fmaf(xv, wx1[1], v1[1] + bb1[1]);
        const float p12 = fmaf(xv, wx1[2], v1[2] + bb1[2]);
        const float p13 = fmaf(xv, wx1[3], v1[3] + bb1[3]);
        const float p20 = fmaf(xv, wx2[0], v2[0] + bb2[0]);
        const float p21 = fmaf(xv, wx2[1], v2[1] + bb2[1]);
        const float p22 = fmaf(xv, wx2[2], v2[2] + bb2[2]);
        const float p23 = fmaf(xv, wx2[3], v2[3] + bb2[3]);

        const float gi1 = fast_sigmoid(p10);
        const float gi2 = fast_sigmoid(p20);
        const float gf1 = fast_sigmoid(p11);
        const float gf2 = fast_sigmoid(p21);
        const float gg1 = fast_tanh(p12);
        const float gg2 = fast_tanh(p22);
        const float go1 = fast_sigmoid(p13);
        const float go2 = fast_sigmoid(p23);
        c1 = fmaf(gf1, c1, gi1 * gg1);
        c2 = fmaf(gf2, c2, gi2 * gg2);
        h1 = go1 * fast_tanh(c1);
        h2 = go2 * fast_tanh(c2);

        hsh[wv][b * HH + u1] = (_Float16)h1;   // next step's B-frag
        hsh[wv][b * HH + u2] = (_Float16)h2;
    }

    // ---- epilogue: out[b] = fc_W . h + fc_b; reduce lanes with same n&3 ----
    float p = h1 * fc_W[u1] + h2 * fc_W[u2];
    #pragma unroll
    for (int m = 4; m <= 32; m <<= 1)
        p += __shfl_xor(p, m, 64);           // over bits 2,3 (r) and 4,5 (q)
    if (lane < 4)
        out[gb0 + lane] = p + fc_b[0];       // lane = b for q=0,r=0
}

extern "C" void kernel_launch(void* const* d_in, const int* in_sizes, int n_in,
                              void* d_out, int out_size, void* d_ws, size_t ws_size,
                              hipStream_t stream) {
    const float* x    = (const float*)d_in[0];
    const float* W_ih = (const float*)d_in[1];
    const float* W_hh = (const float*)d_in[2];
    const float* b_ih = (const float*)d_in[3];
    const float* b_hh = (const float*)d_in[4];
    const float* fc_W = (const float*)d_in[5];
    const float* fc_b = (const float*)d_in[6];
    float* out = (float*)d_out;

    const int B = in_sizes[0] / TT;   // 4096 (D == 1)
    dim3 grid(B / BPB), block(NT);
    lstm_q4<<<grid, block, 0, stream>>>(x, W_ih, W_hh, b_ih, b_hh,
                                        fc_W, fc_b, out);
}